// Round 8
// baseline (228.525 us; speedup 1.0000x reference)
//
#include <hip/hip_runtime.h>
#include <hip/hip_bf16.h>

// SelfAttention N=8, L=1024, E=1024, H=16, D=64  (fp32 in/out, bf16 MFMA inside)
// R8: GEMM T3-minimal prefetch double-buffer (stage t+1 during compute t, one
// barrier/step); merged Q+K GEMM launch; attn mask via v_bfe_i32 (sbfe).
//
// ws layout: @0 Xq->AO | @16M Xk->VTb | @32M Qb | @48M Kb | @64M W4 (8MB)
//            @72M M64 (1MB) | @73M Xv (16MB, used when ws >= 90MB)

typedef __attribute__((ext_vector_type(8))) short short8;
typedef __attribute__((ext_vector_type(8))) __bf16 bf16x8;
typedef __attribute__((ext_vector_type(4))) float f32x4;
typedef __attribute__((ext_vector_type(16))) float f32x16;
typedef __attribute__((ext_vector_type(4))) unsigned short ushort4v;

static __device__ __forceinline__ unsigned short f2bf(float x) {
  union { float f; unsigned u; } v; v.f = x;
  unsigned r = v.u + 0x7FFFu + ((v.u >> 16) & 1u);
  return (unsigned short)(r >> 16);
}

static __device__ __forceinline__ f32x4 mfma16(short8 a, short8 b, f32x4 c) {
  return __builtin_amdgcn_mfma_f32_16x16x32_bf16(
      __builtin_bit_cast(bf16x8, a), __builtin_bit_cast(bf16x8, b), c, 0, 0, 0);
}
static __device__ __forceinline__ f32x16 mfma32(short8 a, short8 b, f32x16 c) {
  return __builtin_amdgcn_mfma_f32_32x32x16_bf16(
      __builtin_bit_cast(bf16x8, a), __builtin_bit_cast(bf16x8, b), c, 0, 0, 0);
}

static __device__ __forceinline__ void gll16(const unsigned short* g, unsigned short* l) {
  __builtin_amdgcn_global_load_lds(
      (const __attribute__((address_space(1))) unsigned int*)(const void*)g,
      (__attribute__((address_space(3))) unsigned int*)(void*)l, 16, 0, 0);
}

static __device__ __forceinline__ unsigned cvtpk(float lo, float hi) {
  unsigned r;
  asm("v_cvt_pk_bf16_f32 %0, %1, %2" : "=v"(r) : "v"(lo), "v"(hi));
  return r;
}

static __device__ __forceinline__ void cvt8(const float* __restrict__ in,
                                            unsigned short* __restrict__ out, int i) {
  float4 a = ((const float4*)in)[i * 2];
  float4 b = ((const float4*)in)[i * 2 + 1];
  union { short8 v; unsigned short u[8]; } pk;
  pk.u[0] = f2bf(a.x); pk.u[1] = f2bf(a.y); pk.u[2] = f2bf(a.z); pk.u[3] = f2bf(a.w);
  pk.u[4] = f2bf(b.x); pk.u[5] = f2bf(b.y); pk.u[6] = f2bf(b.z); pk.u[7] = f2bf(b.w);
  ((short8*)out)[i] = pk.v;
}

// ---------- fused pre-pass: cvt q/k(/v) + 4 weights + maskpack ----------
__global__ __launch_bounds__(256)
void fused_pre(const float* __restrict__ queries, const float* __restrict__ keys,
               const float* __restrict__ values,
               const float* __restrict__ Wq, const float* __restrict__ Wk,
               const float* __restrict__ Wv, const float* __restrict__ Wo,
               const int* __restrict__ mask,
               unsigned short* __restrict__ Xq, unsigned short* __restrict__ Xk,
               unsigned short* __restrict__ Xv,
               unsigned short* __restrict__ W4, unsigned long long* __restrict__ M64)
{
  const int bid = blockIdx.x, tid = threadIdx.x;
  if (bid < 4096) {
    cvt8(queries, Xq, bid * 256 + tid);
  } else if (bid < 8192) {
    cvt8(keys, Xk, (bid - 4096) * 256 + tid);
  } else if (bid < 10240) {
    const int wsel = (bid - 8192) >> 9;
    const float* src = wsel == 0 ? Wq : wsel == 1 ? Wk : wsel == 2 ? Wv : Wo;
    cvt8(src, W4 + wsel * 1048576, ((bid - 8192) & 511) * 256 + tid);
  } else if (bid < 11264) {
    const int lane = tid & 63, wid = tid >> 6;
    const int gw = (bid - 10240) * 4 + wid;
#pragma unroll 4
    for (int j = 0; j < 32; ++j) {
      const int w = gw * 32 + j;
      unsigned long long b = __ballot(mask[(size_t)w * 64 + lane] != 0);
      if (lane == 0) M64[w] = b;
    }
  } else {
    cvt8(values, Xv, (bid - 11264) * 256 + tid);
  }
}

// ---------- fp32 -> bf16 convert (fallback when ws too small for Xv) ----------
__global__ __launch_bounds__(256)
void cvt_kernel(const float* __restrict__ in, unsigned short* __restrict__ out, int n8)
{
  int i = blockIdx.x * 256 + threadIdx.x;
  if (i >= n8) return;
  cvt8(in, out, i);
}

// ---------- 128x128 bf16 GEMM body (A @ B^T + bias), prefetch double-buffer ----
// bid in [0,512): 64 bm x 8 bn, A-panel-per-XCD swizzle (bid&7 = XCD owns 8 bm).
// T3-minimal: stage tile k+1 into buf^1 right after the barrier, compute buf.
// One barrier per K-step; its vmcnt-drain covers loads that flew during MFMA.
template<int MODE>
static __device__ __forceinline__
void gemm_body(const unsigned short* __restrict__ A, const unsigned short* __restrict__ B,
               const float* __restrict__ bias, void* __restrict__ outp,
               float oscale, int bid)
{
  __shared__ alignas(16) unsigned short As[2][4096];
  __shared__ alignas(16) unsigned short Bs[2][4096];
  const int tid = threadIdx.x, lane = tid & 63, wid = tid >> 6;
  const int l15 = lane & 15, lg = lane >> 4;
  const int j = bid >> 3;
  const int bm = (bid & 7) * 8 + (j & 7), bn = j >> 3;
  const int wr = (wid >> 1) * 64, wc = (wid & 1) * 64;

  f32x4 acc[4][4] = {};
  const int o = wid * 1024 + lane * 16;
  const unsigned short* gA0 = A + (size_t)(bm * 128 + (o >> 6)) * 1024 + ((o & 63) >> 1);
  const unsigned short* gA1 = gA0 + 64 * 1024;
  const unsigned short* gB0 = B + (size_t)(bn * 128 + (o >> 6)) * 1024 + ((o & 63) >> 1);
  const unsigned short* gB1 = gB0 + 64 * 1024;
  unsigned short* lA0 = &As[0][0] + wid * 512;
  unsigned short* lA1 = lA0 + 2048;
  unsigned short* lB0 = &Bs[0][0] + wid * 512;
  unsigned short* lB1 = lB0 + 2048;

  // prologue: stage k=0 into buf 0
  gll16(gA0, lA0); gll16(gA1, lA1);
  gll16(gB0, lB0); gll16(gB1, lB1);

  int cur = 0;
#pragma unroll 2
  for (int k0 = 0; k0 < 1024; k0 += 32) {
    __syncthreads();   // drains vmcnt: buf[cur] staged; prior reads of buf[cur^1] done
    if (k0 + 32 < 1024) {
      const int nb = (cur ^ 1) * 4096;
      gll16(gA0 + k0 + 32, lA0 + nb); gll16(gA1 + k0 + 32, lA1 + nb);
      gll16(gB0 + k0 + 32, lB0 + nb); gll16(gB1 + k0 + 32, lB1 + nb);
    }
    const unsigned short* Ab = &As[cur][0];
    const unsigned short* Bb = &Bs[cur][0];
    short8 af[4], bf[4];
#pragma unroll
    for (int f = 0; f < 4; ++f) {
      af[f] = *(const short8*)&Ab[(wr + f * 16 + l15) * 32 + lg * 8];
      bf[f] = *(const short8*)&Bb[(wc + f * 16 + l15) * 32 + lg * 8];
    }
#pragma unroll
    for (int r = 0; r < 4; ++r)
#pragma unroll
      for (int c = 0; c < 4; ++c)
        acc[r][c] = mfma16(af[r], bf[c], acc[r][c]);
    cur ^= 1;
  }

#pragma unroll
  for (int r = 0; r < 4; ++r) {
    const int mb = bm * 128 + wr + r * 16 + lg * 4;
#pragma unroll
    for (int c = 0; c < 4; ++c) {
      const int col = bn * 128 + wc + c * 16 + l15;
      const float bv = bias[col];
      if (MODE == 0) {
        unsigned short* O = (unsigned short*)outp;
#pragma unroll
        for (int i = 0; i < 4; ++i)
          O[(size_t)(mb + i) * 1024 + col] = f2bf((acc[r][c][i] + bv) * oscale);
      } else if (MODE == 1) {
        unsigned short* O = (unsigned short*)outp;
        const int n = mb >> 10, l = mb & 1023, hh = col >> 6, d = col & 63;
        union { ushort4v v; unsigned short u[4]; } pk;
#pragma unroll
        for (int i = 0; i < 4; ++i) pk.u[i] = f2bf(acc[r][c][i] + bv);
        *(ushort4v*)&O[(size_t)((n * 16 + hh) * 64 + d) * 1024 + l] = pk.v;
      } else {
        float* O = (float*)outp;
#pragma unroll
        for (int i = 0; i < 4; ++i)
          O[(size_t)(mb + i) * 1024 + col] = acc[r][c][i] + bv;
      }
    }
  }
}

// merged Q+K projection: grid 1024; region 0 -> Q (scaled), region 1 -> K
__global__ __launch_bounds__(256)
void gemm_qk(const unsigned short* __restrict__ Xq, const unsigned short* __restrict__ Xk,
             const unsigned short* __restrict__ W4,
             const float* __restrict__ bq, const float* __restrict__ bk,
             unsigned short* __restrict__ Qb, unsigned short* __restrict__ Kb, float scq)
{
  const int region = blockIdx.x >> 9;
  gemm_body<0>(region ? Xk : Xq, W4 + region * 1048576, region ? bk : bq,
               region ? (void*)Kb : (void*)Qb, region ? 1.0f : scq, blockIdx.x & 511);
}

__global__ __launch_bounds__(256)
void gemm_v(const unsigned short* __restrict__ A, const unsigned short* __restrict__ B,
            const float* __restrict__ bias, void* __restrict__ outp)
{
  gemm_body<1>(A, B, bias, outp, 1.0f, blockIdx.x);
}

__global__ __launch_bounds__(256)
void gemm_o(const unsigned short* __restrict__ A, const unsigned short* __restrict__ B,
            const float* __restrict__ bias, void* __restrict__ outp)
{
  gemm_body<2>(A, B, bias, outp, 1.0f, blockIdx.x);
}

// ---------- flash attention: fragment-ordered LDS, m=0, half-tile interleave ----------
__global__ __launch_bounds__(256)
void attn_kernel(const unsigned short* __restrict__ Q,   // [8192,1024] bf16 (scaled)
                 const unsigned short* __restrict__ K,   // [8192,1024] bf16
                 const unsigned short* __restrict__ VT,  // [N,H,64,1024] bf16
                 const unsigned long long* __restrict__ M64,  // [N,1024,16]
                 unsigned short* __restrict__ AO)        // [8192,1024] bf16
{
  __shared__ alignas(16) unsigned short KV[2][8192];   // [K:0..4096][V:4096..8192]
  const int tid = threadIdx.x, lane = tid & 63, wid = tid >> 6;
  const int l31 = lane & 31, hi = lane >> 5, hi4 = hi * 4;
  const int w = (blockIdx.x & 7) * 128 + (blockIdx.x >> 3);   // XCD swizzle
  const int qt = w & 7, nh = w >> 3, h = nh & 15, n = nh >> 4;
  const int qbase = qt * 128 + wid * 32;

  const unsigned short* src[4];
  unsigned short* dst0[4];
  int tstride;
  if (wid < 2) {
#pragma unroll
    for (int i = 0; i < 4; ++i) {
      const int g = wid * 4 + i, c = g >> 1, kh = g & 1;
      src[i] = K + ((size_t)(n * 1024 + kh * 32 + l31) << 10) + h * 64 + c * 16 + hi * 8;
      dst0[i] = &KV[0][g * 512];
    }
    tstride = 64 * 1024;
  } else {
#pragma unroll
    for (int i = 0; i < 4; ++i) {
      const int g = (wid - 2) * 4 + i, kt = g >> 1, dh = g & 1;
      src[i] = VT + ((size_t)(nh * 64 + dh * 32 + l31) << 10) + kt * 16 + hi * 8;
      dst0[i] = &KV[0][4096 + g * 512];
    }
    tstride = 64;
  }

  short8 qf[4];
#pragma unroll
  for (int c = 0; c < 4; ++c)
    qf[c] = *(const short8*)&Q[(size_t)(n * 1024 + qbase + l31) * 1024 + h * 64 + c * 16 + hi * 8];

  const unsigned long long* Mq = M64 + (size_t)(n * 1024 + qbase + l31) * 16;
  unsigned long long mw = Mq[0], mwn = 0;

  f32x16 oacc0 = {}, oacc1 = {};
  float l_r = 0.f;

#pragma unroll
  for (int i = 0; i < 4; ++i) gll16(src[i], dst0[i]);

  int cur = 0;
#pragma unroll 2
  for (int t = 0; t < 16; ++t) {
    __syncthreads();
    if (t < 15) {
      const size_t off = (size_t)(t + 1) * tstride;
#pragma unroll
      for (int i = 0; i < 4; ++i) gll16(src[i] + off, dst0[i] + (cur ^ 1) * 8192);
      mwn = Mq[t + 1];
    }
    const unsigned short* Kb = &KV[cur][0];

    f32x16 s0 = {}, s1 = {};
    __builtin_amdgcn_s_setprio(1);
#pragma unroll
    for (int c = 0; c < 4; ++c) {
      short8 kf0 = *(const short8*)&Kb[(c * 2 + 0) * 512 + lane * 8];
      short8 kf1 = *(const short8*)&Kb[(c * 2 + 1) * 512 + lane * 8];
      s0 = mfma32(kf0, qf[c], s0);
      s1 = mfma32(kf1, qf[c], s1);
    }
    __builtin_amdgcn_s_setprio(0);

    const unsigned wlo = (unsigned)mw >> hi4;
    const unsigned whi = (unsigned)(mw >> 32) >> hi4;
#pragma unroll
    for (int kt = 0; kt < 2; ++kt) {
      const unsigned wsh = kt ? whi : wlo;
      const int gb0 = (int)wsh, gb1 = (int)(wsh >> 8),
                gb2 = (int)(wsh >> 16), gb3 = (int)(wsh >> 24);
      const f32x16& sv = kt ? s1 : s0;
      float p[16];
      float lsum = 0.f;
#pragma unroll
      for (int r = 0; r < 16; ++r) {
        const float pe = exp2f(sv[r]);
        const int g = r >> 2;
        const int gbv = (g == 0) ? gb0 : (g == 1) ? gb1 : (g == 2) ? gb2 : gb3;
        const int msk = __builtin_amdgcn_sbfe(gbv, r & 3, 1);   // 0 or -1
        p[r] = __builtin_bit_cast(float, __builtin_bit_cast(int, pe) & msk);
        lsum += p[r];
      }
      l_r += lsum;
      unsigned u[4][2];
#pragma unroll
      for (int g = 0; g < 4; ++g) {
        u[g][0] = cvtpk(p[4 * g], p[4 * g + 1]);
        u[g][1] = cvtpk(p[4 * g + 2], p[4 * g + 3]);
      }
      short8 pa0, pa1;
#pragma unroll
      for (int m = 0; m < 2; ++m) {
        unsigned a0 = u[2 * m][0], b0 = u[2 * m + 1][0];
        unsigned a1 = u[2 * m][1], b1 = u[2 * m + 1][1];
        asm("v_permlane32_swap_b32 %0, %1" : "+v"(a0), "+v"(b0));
        asm("v_permlane32_swap_b32 %0, %1" : "+v"(a1), "+v"(b1));
        union { unsigned uu[4]; short8 v; } pk;
        pk.uu[0] = a0; pk.uu[1] = a1; pk.uu[2] = b0; pk.uu[3] = b1;
        if (m == 0) pa0 = pk.v; else pa1 = pk.v;
      }
      __builtin_amdgcn_s_setprio(1);
      {
        const int g0 = (kt * 2 + 0) * 2, g1 = (kt * 2 + 1) * 2;
        short8 vf00 = *(const short8*)&Kb[4096 + (g0 + 0) * 512 + lane * 8];
        short8 vf01 = *(const short8*)&Kb[4096 + (g0 + 1) * 512 + lane * 8];
        short8 vf10 = *(const short8*)&Kb[4096 + (g1 + 0) * 512 + lane * 8];
        short8 vf11 = *(const short8*)&Kb[4096 + (g1 + 1) * 512 + lane * 8];
        oacc0 = mfma32(pa0, vf00, oacc0);
        oacc1 = mfma32(pa0, vf01, oacc1);
        oacc0 = mfma32(pa1, vf10, oacc0);
        oacc1 = mfma32(pa1, vf11, oacc1);
      }
      __builtin_amdgcn_s_setprio(0);
    }

    mw = mwn;
    cur ^= 1;
  }

  const float l_tot = l_r + __shfl_xor(l_r, 32);
  const float inv_l = 1.0f / l_tot;
  const int invi = __builtin_bit_cast(int, inv_l);
#pragma unroll
  for (int r = 0; r < 16; ++r) {
    const int qrow = 8 * (r >> 2) + (r & 3) + hi4;
    const float rl = __builtin_bit_cast(float, __builtin_amdgcn_ds_bpermute(qrow * 4, invi));
    const size_t row = (size_t)(n * 1024 + qbase + qrow) * 1024 + h * 64;
    AO[row + l31]      = f2bf(oacc0[r] * rl);
    AO[row + 32 + l31] = f2bf(oacc1[r] * rl);
  }
}

extern "C" void kernel_launch(void* const* d_in, const int* in_sizes, int n_in,
                              void* d_out, int out_size, void* d_ws, size_t ws_size,
                              hipStream_t stream) {
  (void)in_sizes; (void)n_in; (void)out_size;
  const float* values  = (const float*)d_in[0];
  const float* keys    = (const float*)d_in[1];
  const float* queries = (const float*)d_in[2];
  const int*   mask    = (const int*)d_in[3];
  const float* Wv = (const float*)d_in[4];
  const float* bv = (const float*)d_in[5];
  const float* Wk = (const float*)d_in[6];
  const float* bk = (const float*)d_in[7];
  const float* Wq = (const float*)d_in[8];
  const float* bq = (const float*)d_in[9];
  const float* Wo = (const float*)d_in[10];
  const float* bo = (const float*)d_in[11];

  const size_t MB = 1u << 20;
  char* ws = (char*)d_ws;
  unsigned short* R0  = (unsigned short*)(ws);             // Xq -> (Xv) -> AO
  unsigned short* R16 = (unsigned short*)(ws + 16 * MB);   // Xk -> VTb
  unsigned short* Qb  = (unsigned short*)(ws + 32 * MB);
  unsigned short* Kb  = (unsigned short*)(ws + 48 * MB);
  unsigned short* W4  = (unsigned short*)(ws + 64 * MB);   // 4 x 1M shorts
  unsigned long long* M64 = (unsigned long long*)(ws + 72 * MB);  // 1MB
  unsigned short* Xv  = (unsigned short*)(ws + 73 * MB);   // 16MB optional
  const bool foldv = ws_size >= 90 * MB;

  const dim3 b256(256);
  const int NX8 = 8 * 1024 * 1024 / 8;
  const float SCFULL = 0.03125f * 1.44269504089f;   // 1/sqrt(E) * log2(e)

  fused_pre<<<dim3(foldv ? 15360 : 11264), b256, 0, stream>>>(
      queries, keys, values, Wq, Wk, Wv, Wo, mask, R0, R16, Xv, W4, M64);
  gemm_qk<<<dim3(1024), b256, 0, stream>>>(R0, R16, W4, bq, bk, Qb, Kb, SCFULL);
  if (!foldv)
    cvt_kernel<<<dim3(4096), b256, 0, stream>>>(values, R0, NX8);       // Xv @ R0
  gemm_v<<<dim3(512), b256, 0, stream>>>(foldv ? Xv : R0, W4 + 2 * 1048576,
                                         bv, (void*)R16);               // VTb
  attn_kernel<<<dim3(1024), b256, 0, stream>>>(Qb, Kb, R16, M64, R0 /*AO*/);
  gemm_o<<<dim3(512), b256, 0, stream>>>(R0, W4 + 3 * 1048576, bo, d_out);
}

// Round 9
// 217.305 us; speedup vs baseline: 1.0516x; 1.0516x over previous
//
#include <hip/hip_runtime.h>
#include <hip/hip_bf16.h>

// SelfAttention N=8, L=1024, E=1024, H=16, D=64  (fp32 in/out, bf16 MFMA inside)
// R9: revert R8 regressions (merged-QK launch broke per-XCD L2 residency; sbfe
// mask cost +24 VGPR). V-GEMM now computes V^T = Wv @ Xv^T directly (MODE 3):
// coalesced u16 stores instead of 8B scatter, output [h*64+d][n*1024+l].
// attn: R7 structure + lacc-MFMA l-sum (no epilogue bpermute, no f32 adds).
//
// ws layout: @0 Xq->AO | @16M Xk->VTb | @32M Qb | @48M Kb | @64M W4 (8MB)
//            @72M M64 (1MB) | @73M Xv (16MB, used when ws >= 90MB)

typedef __attribute__((ext_vector_type(8))) short short8;
typedef __attribute__((ext_vector_type(8))) __bf16 bf16x8;
typedef __attribute__((ext_vector_type(4))) float f32x4;
typedef __attribute__((ext_vector_type(16))) float f32x16;

static __device__ __forceinline__ unsigned short f2bf(float x) {
  union { float f; unsigned u; } v; v.f = x;
  unsigned r = v.u + 0x7FFFu + ((v.u >> 16) & 1u);
  return (unsigned short)(r >> 16);
}

static __device__ __forceinline__ f32x4 mfma16(short8 a, short8 b, f32x4 c) {
  return __builtin_amdgcn_mfma_f32_16x16x32_bf16(
      __builtin_bit_cast(bf16x8, a), __builtin_bit_cast(bf16x8, b), c, 0, 0, 0);
}
static __device__ __forceinline__ f32x16 mfma32(short8 a, short8 b, f32x16 c) {
  return __builtin_amdgcn_mfma_f32_32x32x16_bf16(
      __builtin_bit_cast(bf16x8, a), __builtin_bit_cast(bf16x8, b), c, 0, 0, 0);
}

static __device__ __forceinline__ void gll16(const unsigned short* g, unsigned short* l) {
  __builtin_amdgcn_global_load_lds(
      (const __attribute__((address_space(1))) unsigned int*)(const void*)g,
      (__attribute__((address_space(3))) unsigned int*)(void*)l, 16, 0, 0);
}

static __device__ __forceinline__ unsigned cvtpk(float lo, float hi) {
  unsigned r;
  asm("v_cvt_pk_bf16_f32 %0, %1, %2" : "=v"(r) : "v"(lo), "v"(hi));
  return r;
}

static __device__ __forceinline__ void cvt8(const float* __restrict__ in,
                                            unsigned short* __restrict__ out, int i) {
  float4 a = ((const float4*)in)[i * 2];
  float4 b = ((const float4*)in)[i * 2 + 1];
  union { short8 v; unsigned short u[8]; } pk;
  pk.u[0] = f2bf(a.x); pk.u[1] = f2bf(a.y); pk.u[2] = f2bf(a.z); pk.u[3] = f2bf(a.w);
  pk.u[4] = f2bf(b.x); pk.u[5] = f2bf(b.y); pk.u[6] = f2bf(b.z); pk.u[7] = f2bf(b.w);
  ((short8*)out)[i] = pk.v;
}

// ---------- fused pre-pass: cvt q/k(/v) + 4 weights + maskpack ----------
__global__ __launch_bounds__(256)
void fused_pre(const float* __restrict__ queries, const float* __restrict__ keys,
               const float* __restrict__ values,
               const float* __restrict__ Wq, const float* __restrict__ Wk,
               const float* __restrict__ Wv, const float* __restrict__ Wo,
               const int* __restrict__ mask,
               unsigned short* __restrict__ Xq, unsigned short* __restrict__ Xk,
               unsigned short* __restrict__ Xv,
               unsigned short* __restrict__ W4, unsigned long long* __restrict__ M64)
{
  const int bid = blockIdx.x, tid = threadIdx.x;
  if (bid < 4096) {
    cvt8(queries, Xq, bid * 256 + tid);
  } else if (bid < 8192) {
    cvt8(keys, Xk, (bid - 4096) * 256 + tid);
  } else if (bid < 10240) {
    const int wsel = (bid - 8192) >> 9;
    const float* src = wsel == 0 ? Wq : wsel == 1 ? Wk : wsel == 2 ? Wv : Wo;
    cvt8(src, W4 + wsel * 1048576, ((bid - 8192) & 511) * 256 + tid);
  } else if (bid < 11264) {
    const int lane = tid & 63, wid = tid >> 6;
    const int gw = (bid - 10240) * 4 + wid;
#pragma unroll 4
    for (int j = 0; j < 32; ++j) {
      const int w = gw * 32 + j;
      unsigned long long b = __ballot(mask[(size_t)w * 64 + lane] != 0);
      if (lane == 0) M64[w] = b;
    }
  } else {
    cvt8(values, Xv, (bid - 11264) * 256 + tid);
  }
}

// ---------- fp32 -> bf16 convert (fallback when ws too small for Xv) ----------
__global__ __launch_bounds__(256)
void cvt_kernel(const float* __restrict__ in, unsigned short* __restrict__ out, int n8)
{
  int i = blockIdx.x * 256 + threadIdx.x;
  if (i >= n8) return;
  cvt8(in, out, i);
}

// ---------- 128x128 bf16 GEMM (C = A @ B^T + bias), R7 2-barrier structure ----
// MODE 0: bf16 [M,1024], bias by col, oscale. MODE 2: f32 [M,1024], bias by col.
// MODE 3: bf16 [1024 rows e][8192 cols m] (V^T), bias by ROW; block mapping
//         transposed so XCD (bid&7) owns 8 bn-tiles (2MB B-panel + 2MB A in L2).
template<int MODE>
__global__ __launch_bounds__(256)
void gemm_kernel(const unsigned short* __restrict__ A, const unsigned short* __restrict__ B,
                 const float* __restrict__ bias, void* __restrict__ outp, float oscale)
{
  __shared__ alignas(16) unsigned short As[128][32];
  __shared__ alignas(16) unsigned short Bs[128][32];
  const int tid = threadIdx.x, lane = tid & 63, wid = tid >> 6;
  const int l15 = lane & 15, lg = lane >> 4;
  const int j = blockIdx.x >> 3;
  int bm, bn;
  if (MODE == 3) { bn = (blockIdx.x & 7) * 8 + (j & 7); bm = j >> 3; }
  else           { bm = (blockIdx.x & 7) * 8 + (j & 7); bn = j >> 3; }
  const int wr = (wid >> 1) * 64, wc = (wid & 1) * 64;

  f32x4 acc[4][4] = {};
  const int o = wid * 1024 + lane * 16;
  const unsigned short* gA0 = A + (size_t)(bm * 128 + (o >> 6)) * 1024 + ((o & 63) >> 1);
  const unsigned short* gA1 = gA0 + 64 * 1024;
  const unsigned short* gB0 = B + (size_t)(bn * 128 + (o >> 6)) * 1024 + ((o & 63) >> 1);
  const unsigned short* gB1 = gB0 + 64 * 1024;
  unsigned short* lA0 = &As[0][0] + wid * 512;
  unsigned short* lA1 = lA0 + 2048;
  unsigned short* lB0 = &Bs[0][0] + wid * 512;
  unsigned short* lB1 = lB0 + 2048;

  for (int k0 = 0; k0 < 1024; k0 += 32) {
    __syncthreads();
    gll16(gA0 + k0, lA0); gll16(gA1 + k0, lA1);
    gll16(gB0 + k0, lB0); gll16(gB1 + k0, lB1);
    __syncthreads();
    short8 af[4], bf[4];
#pragma unroll
    for (int f = 0; f < 4; ++f) {
      af[f] = *(const short8*)&As[wr + f * 16 + l15][lg * 8];
      bf[f] = *(const short8*)&Bs[wc + f * 16 + l15][lg * 8];
    }
#pragma unroll
    for (int r = 0; r < 4; ++r)
#pragma unroll
      for (int c = 0; c < 4; ++c)
        acc[r][c] = mfma16(af[r], bf[c], acc[r][c]);
  }

#pragma unroll
  for (int r = 0; r < 4; ++r) {
    const int mb = bm * 128 + wr + r * 16 + lg * 4;
#pragma unroll
    for (int c = 0; c < 4; ++c) {
      const int col = bn * 128 + wc + c * 16 + l15;
      if (MODE == 0) {
        const float bv = bias[col];
        unsigned short* O = (unsigned short*)outp;
#pragma unroll
        for (int i = 0; i < 4; ++i)
          O[(size_t)(mb + i) * 1024 + col] = f2bf((acc[r][c][i] + bv) * oscale);
      } else if (MODE == 3) {      // V^T: row = e, col = m; bias by row; coalesced
        unsigned short* O = (unsigned short*)outp;
#pragma unroll
        for (int i = 0; i < 4; ++i)
          O[(size_t)(mb + i) * 8192 + col] = f2bf(acc[r][c][i] + bias[mb + i]);
      } else {
        const float bv = bias[col];
        float* O = (float*)outp;
#pragma unroll
        for (int i = 0; i < 4; ++i)
          O[(size_t)(mb + i) * 1024 + col] = acc[r][c][i] + bv;
      }
    }
  }
}

// ---------- flash attention: fragment-ordered LDS, m=0, lacc-MFMA l-sum ----------
// Block: 4 waves, 128 q of one (n,h). K+V double-buffered (32KB).
// Q pre-scaled by SC*log2e -> p = exp2(s). VT layout: [h*64+d][n*1024+l].
__global__ __launch_bounds__(256)
void attn_kernel(const unsigned short* __restrict__ Q,   // [8192,1024] bf16 (scaled)
                 const unsigned short* __restrict__ K,   // [8192,1024] bf16
                 const unsigned short* __restrict__ VT,  // [1024][8192] bf16 (V^T)
                 const unsigned long long* __restrict__ M64,  // [N,1024,16]
                 unsigned short* __restrict__ AO)        // [8192,1024] bf16
{
  __shared__ alignas(16) unsigned short KV[2][8192];   // [K:0..4096][V:4096..8192]
  const int tid = threadIdx.x, lane = tid & 63, wid = tid >> 6;
  const int l31 = lane & 31, hi = lane >> 5, hi4 = hi * 4;
  const int w = (blockIdx.x & 7) * 128 + (blockIdx.x >> 3);   // XCD swizzle
  const int qt = w & 7, nh = w >> 3, h = nh & 15, n = nh >> 4;
  const int qbase = qt * 128 + wid * 32;

  // staging: waves 0,1 -> K groups 0..7; waves 2,3 -> V groups 0..7
  const unsigned short* src[4];
  unsigned short* dst0[4];
  int tstride;
  if (wid < 2) {
#pragma unroll
    for (int i = 0; i < 4; ++i) {
      const int g = wid * 4 + i, c = g >> 1, kh = g & 1;
      src[i] = K + ((size_t)(n * 1024 + kh * 32 + l31) << 10) + h * 64 + c * 16 + hi * 8;
      dst0[i] = &KV[0][g * 512];
    }
    tstride = 64 * 1024;
  } else {
#pragma unroll
    for (int i = 0; i < 4; ++i) {
      const int g = (wid - 2) * 4 + i, kt = g >> 1, dh = g & 1;
      src[i] = VT + (size_t)(h * 64 + dh * 32 + l31) * 8192 + n * 1024 + kt * 16 + hi * 8;
      dst0[i] = &KV[0][4096 + g * 512];
    }
    tstride = 64;
  }

  short8 qf[4];
#pragma unroll
  for (int c = 0; c < 4; ++c)
    qf[c] = *(const short8*)&Q[(size_t)(n * 1024 + qbase + l31) * 1024 + h * 64 + c * 16 + hi * 8];

  const unsigned long long* Mq = M64 + (size_t)(n * 1024 + qbase + l31) * 16;
  unsigned long long mw = Mq[0], mwn = 0;

  f32x16 oacc0 = {}, oacc1 = {}, lacc = {};
  short8 ones;
#pragma unroll
  for (int j = 0; j < 8; ++j) ones[j] = (short)0x3F80;   // bf16 1.0

#pragma unroll
  for (int i = 0; i < 4; ++i) gll16(src[i], dst0[i]);

  int cur = 0;
#pragma unroll 2
  for (int t = 0; t < 16; ++t) {
    __syncthreads();   // drains vmcnt: buf[cur] staged; prev reads of buf[cur^1] done
    if (t < 15) {
      const size_t off = (size_t)(t + 1) * tstride;
#pragma unroll
      for (int i = 0; i < 4; ++i) gll16(src[i] + off, dst0[i] + (cur ^ 1) * 8192);
      mwn = Mq[t + 1];
    }
    const unsigned short* Kb = &KV[cur][0];

    // QK^T swapped: S^T with q = l31 lane-local (Q pre-scaled -> exp2 domain)
    f32x16 s0 = {}, s1 = {};
    __builtin_amdgcn_s_setprio(1);
#pragma unroll
    for (int c = 0; c < 4; ++c) {
      short8 kf0 = *(const short8*)&Kb[(c * 2 + 0) * 512 + lane * 8];
      short8 kf1 = *(const short8*)&Kb[(c * 2 + 1) * 512 + lane * 8];
      s0 = mfma32(kf0, qf[c], s0);
      s1 = mfma32(kf1, qf[c], s1);
    }
    __builtin_amdgcn_s_setprio(0);

    // half-tile: exp/pack(keys 0..31) -> PV kt01 -> exp/pack(32..63) -> PV kt23
    const unsigned wlo = (unsigned)mw >> hi4;
    const unsigned whi = (unsigned)(mw >> 32) >> hi4;
#pragma unroll
    for (int kt = 0; kt < 2; ++kt) {
      const unsigned wsh = kt ? whi : wlo;
      const f32x16& sv = kt ? s1 : s0;
      float p[16];
#pragma unroll
      for (int r = 0; r < 16; ++r) {
        const float pe = exp2f(sv[r]);
        const int pos = 8 * (r >> 2) + (r & 3);
        const int msk = ((int)(wsh << (31 - pos))) >> 31;   // 0 or -1
        p[r] = __builtin_bit_cast(float, __builtin_bit_cast(int, pe) & msk);
      }
      unsigned u[4][2];
#pragma unroll
      for (int g = 0; g < 4; ++g) {
        u[g][0] = cvtpk(p[4 * g], p[4 * g + 1]);
        u[g][1] = cvtpk(p[4 * g + 2], p[4 * g + 3]);
      }
      short8 pa0, pa1;
#pragma unroll
      for (int m = 0; m < 2; ++m) {
        unsigned a0 = u[2 * m][0], b0 = u[2 * m + 1][0];
        unsigned a1 = u[2 * m][1], b1 = u[2 * m + 1][1];
        asm("v_permlane32_swap_b32 %0, %1" : "+v"(a0), "+v"(b0));
        asm("v_permlane32_swap_b32 %0, %1" : "+v"(a1), "+v"(b1));
        union { unsigned uu[4]; short8 v; } pk;
        pk.uu[0] = a0; pk.uu[1] = a1; pk.uu[2] = b0; pk.uu[3] = b1;
        if (m == 0) pa0 = pk.v; else pa1 = pk.v;
      }
      // PV + lacc for this half's two k-slots
      __builtin_amdgcn_s_setprio(1);
      {
        const int g0 = (kt * 2 + 0) * 2, g1 = (kt * 2 + 1) * 2;
        short8 vf00 = *(const short8*)&Kb[4096 + (g0 + 0) * 512 + lane * 8];
        short8 vf01 = *(const short8*)&Kb[4096 + (g0 + 1) * 512 + lane * 8];
        short8 vf10 = *(const short8*)&Kb[4096 + (g1 + 0) * 512 + lane * 8];
        short8 vf11 = *(const short8*)&Kb[4096 + (g1 + 1) * 512 + lane * 8];
        oacc0 = mfma32(pa0, vf00, oacc0);
        oacc1 = mfma32(pa0, vf01, oacc1);
        lacc  = mfma32(pa0, ones, lacc);
        oacc0 = mfma32(pa1, vf10, oacc0);
        oacc1 = mfma32(pa1, vf11, oacc1);
        lacc  = mfma32(pa1, ones, lacc);
      }
      __builtin_amdgcn_s_setprio(0);
    }

    mw = mwn;
    cur ^= 1;
  }

  // epilogue: lacc[r] = l of the same q-row as oacc*[r] (reg-aligned, no shuffles)
#pragma unroll
  for (int r = 0; r < 16; ++r) {
    const int qrow = 8 * (r >> 2) + (r & 3) + hi4;
    const float rl = 1.0f / lacc[r];
    const size_t row = (size_t)(n * 1024 + qbase + qrow) * 1024 + h * 64;
    AO[row + l31]      = f2bf(oacc0[r] * rl);
    AO[row + 32 + l31] = f2bf(oacc1[r] * rl);
  }
}

extern "C" void kernel_launch(void* const* d_in, const int* in_sizes, int n_in,
                              void* d_out, int out_size, void* d_ws, size_t ws_size,
                              hipStream_t stream) {
  (void)in_sizes; (void)n_in; (void)out_size;
  const float* values  = (const float*)d_in[0];
  const float* keys    = (const float*)d_in[1];
  const float* queries = (const float*)d_in[2];
  const int*   mask    = (const int*)d_in[3];
  const float* Wv = (const float*)d_in[4];
  const float* bv = (const float*)d_in[5];
  const float* Wk = (const float*)d_in[6];
  const float* bk = (const float*)d_in[7];
  const float* Wq = (const float*)d_in[8];
  const float* bq = (const float*)d_in[9];
  const float* Wo = (const float*)d_in[10];
  const float* bo = (const float*)d_in[11];

  const size_t MB = 1u << 20;
  char* ws = (char*)d_ws;
  unsigned short* R0  = (unsigned short*)(ws);             // Xq -> (Xv) -> AO
  unsigned short* R16 = (unsigned short*)(ws + 16 * MB);   // Xk -> VTb
  unsigned short* Qb  = (unsigned short*)(ws + 32 * MB);
  unsigned short* Kb  = (unsigned short*)(ws + 48 * MB);
  unsigned short* W4  = (unsigned short*)(ws + 64 * MB);   // 4 x 1M shorts
  unsigned long long* M64 = (unsigned long long*)(ws + 72 * MB);  // 1MB
  unsigned short* Xv  = (unsigned short*)(ws + 73 * MB);   // 16MB optional
  const bool foldv = ws_size >= 90 * MB;

  const dim3 b256(256);
  const int NX8 = 8 * 1024 * 1024 / 8;
  const float SCFULL = 0.03125f * 1.44269504089f;   // 1/sqrt(E) * log2(e)

  fused_pre<<<dim3(foldv ? 15360 : 11264), b256, 0, stream>>>(
      queries, keys, values, Wq, Wk, Wv, Wo, mask, R0, R16, Xv, W4, M64);
  gemm_kernel<0><<<dim3(512), b256, 0, stream>>>(R0,  W4,           bq, (void*)Qb, SCFULL);
  gemm_kernel<0><<<dim3(512), b256, 0, stream>>>(R16, W4 + 1048576, bk, (void*)Kb, 1.0f);
  if (!foldv)
    cvt_kernel<<<dim3(4096), b256, 0, stream>>>(values, R0, NX8);       // Xv @ R0
  // V^T = Wv @ Xv^T  (A = Wv, B = Xv)  -> [1024][8192] coalesced
  gemm_kernel<3><<<dim3(512), b256, 0, stream>>>(W4 + 2 * 1048576, foldv ? Xv : R0,
                                                 bv, (void*)R16, 1.0f);
  attn_kernel<<<dim3(1024), b256, 0, stream>>>(Qb, Kb, R16, M64, R0 /*AO*/);
  gemm_kernel<2><<<dim3(512), b256, 0, stream>>>(R0, W4 + 3 * 1048576, bo, d_out, 1.0f);
}

// Round 12
// 213.787 us; speedup vs baseline: 1.0689x; 1.0165x over previous
//
#include <hip/hip_runtime.h>
#include <hip/hip_bf16.h>

// SelfAttention N=8, L=1024, E=1024, H=16, D=64  (fp32 in/out, bf16 MFMA inside)
// R12: exact R9 kernels (proven PASS @217us); EM experiment abandoned after two
// failures. One safe delta: Xv lives in d_out (dead until final O-GEMM), so the
// values-cvt folds unconditionally into fused_pre (no foldv branch, no separate
// cvt launch), ws use capped at proven 73MB.
//
// ws layout (73MB): @0 Xq->AO | @16M Xk->VTb | @32M Qb | @48M Kb
//                   @64M W4 (8MB) | @72M M64 (1MB)
// d_out (32MB): Xv bf16 [0..16MB) until gemm<3> consumes it; O-GEMM overwrites all.

typedef __attribute__((ext_vector_type(8))) short short8;
typedef __attribute__((ext_vector_type(8))) __bf16 bf16x8;
typedef __attribute__((ext_vector_type(4))) float f32x4;
typedef __attribute__((ext_vector_type(16))) float f32x16;

static __device__ __forceinline__ unsigned short f2bf(float x) {
  union { float f; unsigned u; } v; v.f = x;
  unsigned r = v.u + 0x7FFFu + ((v.u >> 16) & 1u);
  return (unsigned short)(r >> 16);
}

static __device__ __forceinline__ f32x4 mfma16(short8 a, short8 b, f32x4 c) {
  return __builtin_amdgcn_mfma_f32_16x16x32_bf16(
      __builtin_bit_cast(bf16x8, a), __builtin_bit_cast(bf16x8, b), c, 0, 0, 0);
}
static __device__ __forceinline__ f32x16 mfma32(short8 a, short8 b, f32x16 c) {
  return __builtin_amdgcn_mfma_f32_32x32x16_bf16(
      __builtin_bit_cast(bf16x8, a), __builtin_bit_cast(bf16x8, b), c, 0, 0, 0);
}

static __device__ __forceinline__ void gll16(const unsigned short* g, unsigned short* l) {
  __builtin_amdgcn_global_load_lds(
      (const __attribute__((address_space(1))) unsigned int*)(const void*)g,
      (__attribute__((address_space(3))) unsigned int*)(void*)l, 16, 0, 0);
}

static __device__ __forceinline__ unsigned cvtpk(float lo, float hi) {
  unsigned r;
  asm("v_cvt_pk_bf16_f32 %0, %1, %2" : "=v"(r) : "v"(lo), "v"(hi));
  return r;
}

static __device__ __forceinline__ void cvt8(const float* __restrict__ in,
                                            unsigned short* __restrict__ out, int i) {
  float4 a = ((const float4*)in)[i * 2];
  float4 b = ((const float4*)in)[i * 2 + 1];
  union { short8 v; unsigned short u[8]; } pk;
  pk.u[0] = f2bf(a.x); pk.u[1] = f2bf(a.y); pk.u[2] = f2bf(a.z); pk.u[3] = f2bf(a.w);
  pk.u[4] = f2bf(b.x); pk.u[5] = f2bf(b.y); pk.u[6] = f2bf(b.z); pk.u[7] = f2bf(b.w);
  ((short8*)out)[i] = pk.v;
}

// ---------- fused pre-pass: cvt q/k/v + 4 weights + maskpack ----------
__global__ __launch_bounds__(256)
void fused_pre(const float* __restrict__ queries, const float* __restrict__ keys,
               const float* __restrict__ values,
               const float* __restrict__ Wq, const float* __restrict__ Wk,
               const float* __restrict__ Wv, const float* __restrict__ Wo,
               const int* __restrict__ mask,
               unsigned short* __restrict__ Xq, unsigned short* __restrict__ Xk,
               unsigned short* __restrict__ Xv,
               unsigned short* __restrict__ W4, unsigned long long* __restrict__ M64)
{
  const int bid = blockIdx.x, tid = threadIdx.x;
  if (bid < 4096) {
    cvt8(queries, Xq, bid * 256 + tid);
  } else if (bid < 8192) {
    cvt8(keys, Xk, (bid - 4096) * 256 + tid);
  } else if (bid < 10240) {
    const int wsel = (bid - 8192) >> 9;
    const float* src = wsel == 0 ? Wq : wsel == 1 ? Wk : wsel == 2 ? Wv : Wo;
    cvt8(src, W4 + wsel * 1048576, ((bid - 8192) & 511) * 256 + tid);
  } else if (bid < 11264) {
    const int lane = tid & 63, wid = tid >> 6;
    const int gw = (bid - 10240) * 4 + wid;
#pragma unroll 4
    for (int j = 0; j < 32; ++j) {
      const int w = gw * 32 + j;
      unsigned long long b = __ballot(mask[(size_t)w * 64 + lane] != 0);
      if (lane == 0) M64[w] = b;
    }
  } else {
    cvt8(values, Xv, (bid - 11264) * 256 + tid);
  }
}

// ---------- 128x128 bf16 GEMM (C = A @ B^T + bias), 2-barrier structure ----
// MODE 0: bf16 [M,1024], bias by col, oscale. MODE 2: f32 [M,1024], bias by col.
// MODE 3: bf16 [1024 rows e][8192 cols m] (V^T), bias by ROW; block mapping
//         transposed so XCD (bid&7) owns 8 bn-tiles (B-panel L2-resident).
template<int MODE>
__global__ __launch_bounds__(256)
void gemm_kernel(const unsigned short* __restrict__ A, const unsigned short* __restrict__ B,
                 const float* __restrict__ bias, void* __restrict__ outp, float oscale)
{
  __shared__ alignas(16) unsigned short As[128][32];
  __shared__ alignas(16) unsigned short Bs[128][32];
  const int tid = threadIdx.x, lane = tid & 63, wid = tid >> 6;
  const int l15 = lane & 15, lg = lane >> 4;
  const int j = blockIdx.x >> 3;
  int bm, bn;
  if (MODE == 3) { bn = (blockIdx.x & 7) * 8 + (j & 7); bm = j >> 3; }
  else           { bm = (blockIdx.x & 7) * 8 + (j & 7); bn = j >> 3; }
  const int wr = (wid >> 1) * 64, wc = (wid & 1) * 64;

  f32x4 acc[4][4] = {};
  const int o = wid * 1024 + lane * 16;
  const unsigned short* gA0 = A + (size_t)(bm * 128 + (o >> 6)) * 1024 + ((o & 63) >> 1);
  const unsigned short* gA1 = gA0 + 64 * 1024;
  const unsigned short* gB0 = B + (size_t)(bn * 128 + (o >> 6)) * 1024 + ((o & 63) >> 1);
  const unsigned short* gB1 = gB0 + 64 * 1024;
  unsigned short* lA0 = &As[0][0] + wid * 512;
  unsigned short* lA1 = lA0 + 2048;
  unsigned short* lB0 = &Bs[0][0] + wid * 512;
  unsigned short* lB1 = lB0 + 2048;

  for (int k0 = 0; k0 < 1024; k0 += 32) {
    __syncthreads();
    gll16(gA0 + k0, lA0); gll16(gA1 + k0, lA1);
    gll16(gB0 + k0, lB0); gll16(gB1 + k0, lB1);
    __syncthreads();
    short8 af[4], bf[4];
#pragma unroll
    for (int f = 0; f < 4; ++f) {
      af[f] = *(const short8*)&As[wr + f * 16 + l15][lg * 8];
      bf[f] = *(const short8*)&Bs[wc + f * 16 + l15][lg * 8];
    }
#pragma unroll
    for (int r = 0; r < 4; ++r)
#pragma unroll
      for (int c = 0; c < 4; ++c)
        acc[r][c] = mfma16(af[r], bf[c], acc[r][c]);
  }

#pragma unroll
  for (int r = 0; r < 4; ++r) {
    const int mb = bm * 128 + wr + r * 16 + lg * 4;
#pragma unroll
    for (int c = 0; c < 4; ++c) {
      const int col = bn * 128 + wc + c * 16 + l15;
      if (MODE == 0) {
        const float bv = bias[col];
        unsigned short* O = (unsigned short*)outp;
#pragma unroll
        for (int i = 0; i < 4; ++i)
          O[(size_t)(mb + i) * 1024 + col] = f2bf((acc[r][c][i] + bv) * oscale);
      } else if (MODE == 3) {      // V^T: row = e, col = m; bias by row; coalesced
        unsigned short* O = (unsigned short*)outp;
#pragma unroll
        for (int i = 0; i < 4; ++i)
          O[(size_t)(mb + i) * 8192 + col] = f2bf(acc[r][c][i] + bias[mb + i]);
      } else {
        const float bv = bias[col];
        float* O = (float*)outp;
#pragma unroll
        for (int i = 0; i < 4; ++i)
          O[(size_t)(mb + i) * 1024 + col] = acc[r][c][i] + bv;
      }
    }
  }
}

// ---------- flash attention: fragment-ordered LDS, m=0, lacc-MFMA l-sum ----------
// Block: 4 waves, 128 q of one (n,h). K+V double-buffered (32KB).
// Q pre-scaled by SC*log2e -> p = exp2(s). VT layout: [h*64+d][n*1024+l].
__global__ __launch_bounds__(256)
void attn_kernel(const unsigned short* __restrict__ Q,   // [8192,1024] bf16 (scaled)
                 const unsigned short* __restrict__ K,   // [8192,1024] bf16
                 const unsigned short* __restrict__ VT,  // [1024][8192] bf16 (V^T)
                 const unsigned long long* __restrict__ M64,  // [N,1024,16]
                 unsigned short* __restrict__ AO)        // [8192,1024] bf16
{
  __shared__ alignas(16) unsigned short KV[2][8192];   // [K:0..4096][V:4096..8192]
  const int tid = threadIdx.x, lane = tid & 63, wid = tid >> 6;
  const int l31 = lane & 31, hi = lane >> 5, hi4 = hi * 4;
  const int w = (blockIdx.x & 7) * 128 + (blockIdx.x >> 3);   // XCD swizzle
  const int qt = w & 7, nh = w >> 3, h = nh & 15, n = nh >> 4;
  const int qbase = qt * 128 + wid * 32;

  // staging: waves 0,1 -> K groups 0..7; waves 2,3 -> V groups 0..7
  const unsigned short* src[4];
  unsigned short* dst0[4];
  int tstride;
  if (wid < 2) {
#pragma unroll
    for (int i = 0; i < 4; ++i) {
      const int g = wid * 4 + i, c = g >> 1, kh = g & 1;
      src[i] = K + ((size_t)(n * 1024 + kh * 32 + l31) << 10) + h * 64 + c * 16 + hi * 8;
      dst0[i] = &KV[0][g * 512];
    }
    tstride = 64 * 1024;
  } else {
#pragma unroll
    for (int i = 0; i < 4; ++i) {
      const int g = (wid - 2) * 4 + i, kt = g >> 1, dh = g & 1;
      src[i] = VT + (size_t)(h * 64 + dh * 32 + l31) * 8192 + n * 1024 + kt * 16 + hi * 8;
      dst0[i] = &KV[0][4096 + g * 512];
    }
    tstride = 64;
  }

  short8 qf[4];
#pragma unroll
  for (int c = 0; c < 4; ++c)
    qf[c] = *(const short8*)&Q[(size_t)(n * 1024 + qbase + l31) * 1024 + h * 64 + c * 16 + hi * 8];

  const unsigned long long* Mq = M64 + (size_t)(n * 1024 + qbase + l31) * 16;
  unsigned long long mw = Mq[0], mwn = 0;

  f32x16 oacc0 = {}, oacc1 = {}, lacc = {};
  short8 ones;
#pragma unroll
  for (int j = 0; j < 8; ++j) ones[j] = (short)0x3F80;   // bf16 1.0

#pragma unroll
  for (int i = 0; i < 4; ++i) gll16(src[i], dst0[i]);

  int cur = 0;
#pragma unroll 2
  for (int t = 0; t < 16; ++t) {
    __syncthreads();   // drains vmcnt: buf[cur] staged; prev reads of buf[cur^1] done
    if (t < 15) {
      const size_t off = (size_t)(t + 1) * tstride;
#pragma unroll
      for (int i = 0; i < 4; ++i) gll16(src[i] + off, dst0[i] + (cur ^ 1) * 8192);
      mwn = Mq[t + 1];
    }
    const unsigned short* Kb = &KV[cur][0];

    // QK^T swapped: S^T with q = l31 lane-local (Q pre-scaled -> exp2 domain)
    f32x16 s0 = {}, s1 = {};
    __builtin_amdgcn_s_setprio(1);
#pragma unroll
    for (int c = 0; c < 4; ++c) {
      short8 kf0 = *(const short8*)&Kb[(c * 2 + 0) * 512 + lane * 8];
      short8 kf1 = *(const short8*)&Kb[(c * 2 + 1) * 512 + lane * 8];
      s0 = mfma32(kf0, qf[c], s0);
      s1 = mfma32(kf1, qf[c], s1);
    }
    __builtin_amdgcn_s_setprio(0);

    // half-tile: exp/pack(keys 0..31) -> PV kt01 -> exp/pack(32..63) -> PV kt23
    const unsigned wlo = (unsigned)mw >> hi4;
    const unsigned whi = (unsigned)(mw >> 32) >> hi4;
#pragma unroll
    for (int kt = 0; kt < 2; ++kt) {
      const unsigned wsh = kt ? whi : wlo;
      const f32x16& sv = kt ? s1 : s0;
      float p[16];
#pragma unroll
      for (int r = 0; r < 16; ++r) {
        const float pe = exp2f(sv[r]);
        const int pos = 8 * (r >> 2) + (r & 3);
        const int msk = ((int)(wsh << (31 - pos))) >> 31;   // 0 or -1
        p[r] = __builtin_bit_cast(float, __builtin_bit_cast(int, pe) & msk);
      }
      unsigned u[4][2];
#pragma unroll
      for (int g = 0; g < 4; ++g) {
        u[g][0] = cvtpk(p[4 * g], p[4 * g + 1]);
        u[g][1] = cvtpk(p[4 * g + 2], p[4 * g + 3]);
      }
      short8 pa0, pa1;
#pragma unroll
      for (int m = 0; m < 2; ++m) {
        unsigned a0 = u[2 * m][0], b0 = u[2 * m + 1][0];
        unsigned a1 = u[2 * m][1], b1 = u[2 * m + 1][1];
        asm("v_permlane32_swap_b32 %0, %1" : "+v"(a0), "+v"(b0));
        asm("v_permlane32_swap_b32 %0, %1" : "+v"(a1), "+v"(b1));
        union { unsigned uu[4]; short8 v; } pk;
        pk.uu[0] = a0; pk.uu[1] = a1; pk.uu[2] = b0; pk.uu[3] = b1;
        if (m == 0) pa0 = pk.v; else pa1 = pk.v;
      }
      // PV + lacc for this half's two k-slots
      __builtin_amdgcn_s_setprio(1);
      {
        const int g0 = (kt * 2 + 0) * 2, g1 = (kt * 2 + 1) * 2;
        short8 vf00 = *(const short8*)&Kb[4096 + (g0 + 0) * 512 + lane * 8];
        short8 vf01 = *(const short8*)&Kb[4096 + (g0 + 1) * 512 + lane * 8];
        short8 vf10 = *(const short8*)&Kb[4096 + (g1 + 0) * 512 + lane * 8];
        short8 vf11 = *(const short8*)&Kb[4096 + (g1 + 1) * 512 + lane * 8];
        oacc0 = mfma32(pa0, vf00, oacc0);
        oacc1 = mfma32(pa0, vf01, oacc1);
        lacc  = mfma32(pa0, ones, lacc);
        oacc0 = mfma32(pa1, vf10, oacc0);
        oacc1 = mfma32(pa1, vf11, oacc1);
        lacc  = mfma32(pa1, ones, lacc);
      }
      __builtin_amdgcn_s_setprio(0);
    }

    mw = mwn;
    cur ^= 1;
  }

  // epilogue: lacc[r] = l of the same q-row as oacc*[r] (reg-aligned, no shuffles)
#pragma unroll
  for (int r = 0; r < 16; ++r) {
    const int qrow = 8 * (r >> 2) + (r & 3) + hi4;
    const float rl = 1.0f / lacc[r];
    const size_t row = (size_t)(n * 1024 + qbase + qrow) * 1024 + h * 64;
    AO[row + l31]      = f2bf(oacc0[r] * rl);
    AO[row + 32 + l31] = f2bf(oacc1[r] * rl);
  }
}

extern "C" void kernel_launch(void* const* d_in, const int* in_sizes, int n_in,
                              void* d_out, int out_size, void* d_ws, size_t ws_size,
                              hipStream_t stream) {
  (void)in_sizes; (void)n_in; (void)out_size; (void)ws_size;
  const float* values  = (const float*)d_in[0];
  const float* keys    = (const float*)d_in[1];
  const float* queries = (const float*)d_in[2];
  const int*   mask    = (const int*)d_in[3];
  const float* Wv = (const float*)d_in[4];
  const float* bv = (const float*)d_in[5];
  const float* Wk = (const float*)d_in[6];
  const float* bk = (const float*)d_in[7];
  const float* Wq = (const float*)d_in[8];
  const float* bq = (const float*)d_in[9];
  const float* Wo = (const float*)d_in[10];
  const float* bo = (const float*)d_in[11];

  const size_t MB = 1u << 20;
  char* ws = (char*)d_ws;
  unsigned short* R0  = (unsigned short*)(ws);             // Xq -> AO
  unsigned short* R16 = (unsigned short*)(ws + 16 * MB);   // Xk -> VTb
  unsigned short* Qb  = (unsigned short*)(ws + 32 * MB);
  unsigned short* Kb  = (unsigned short*)(ws + 48 * MB);
  unsigned short* W4  = (unsigned short*)(ws + 64 * MB);   // 4 x 1M shorts
  unsigned long long* M64 = (unsigned long long*)(ws + 72 * MB);  // 1MB
  unsigned short* Xv  = (unsigned short*)d_out;            // 16MB of d_out (32MB),
                                                           // dead until O-GEMM

  const dim3 b256(256);
  const float SCFULL = 0.03125f * 1.44269504089f;   // 1/sqrt(E) * log2(e)

  fused_pre<<<dim3(15360), b256, 0, stream>>>(
      queries, keys, values, Wq, Wk, Wv, Wo, mask, R0, R16, Xv, W4, M64);
  gemm_kernel<0><<<dim3(512), b256, 0, stream>>>(R0,  W4,           bq, (void*)Qb, SCFULL);
  gemm_kernel<0><<<dim3(512), b256, 0, stream>>>(R16, W4 + 1048576, bk, (void*)Kb, 1.0f);
  // V^T = Wv @ Xv^T  (A = Wv, B = Xv)  -> [1024][8192] coalesced
  gemm_kernel<3><<<dim3(512), b256, 0, stream>>>(W4 + 2 * 1048576, Xv,
                                                 bv, (void*)R16, 1.0f);
  attn_kernel<<<dim3(1024), b256, 0, stream>>>(Qb, Kb, R16, M64, R0 /*AO*/);
  gemm_kernel<2><<<dim3(512), b256, 0, stream>>>(R0, W4 + 3 * 1048576, bo, d_out, 1.0f);
}

// Round 13
// 211.918 us; speedup vs baseline: 1.0784x; 1.0088x over previous
//
#include <hip/hip_runtime.h>
#include <hip/hip_bf16.h>

// SelfAttention N=8, L=1024, E=1024, H=16, D=64  (fp32 in/out, bf16 MFMA inside)
// R13: GEMM rebuilt as BK=64 double-buffered single-barrier (16 iters, stage(k+1)
// issued before compute(k)) with XOR chunk-swizzle (pre-swizzled gll16 source,
// linear LDS, swizzled ds_read) -> conflict-free fragment reads.
// attn + fused_pre + buffer plan frozen from R12 (PASS @213.8us).
//
// ws layout (73MB): @0 Xq->AO | @16M Xk->VTb | @32M Qb | @48M Kb
//                   @64M W4 (8MB) | @72M M64 (1MB)
// d_out (32MB): Xv bf16 [0..16MB) until gemm<3> consumes it; O-GEMM overwrites.

typedef __attribute__((ext_vector_type(8))) short short8;
typedef __attribute__((ext_vector_type(8))) __bf16 bf16x8;
typedef __attribute__((ext_vector_type(4))) float f32x4;
typedef __attribute__((ext_vector_type(16))) float f32x16;

static __device__ __forceinline__ unsigned short f2bf(float x) {
  union { float f; unsigned u; } v; v.f = x;
  unsigned r = v.u + 0x7FFFu + ((v.u >> 16) & 1u);
  return (unsigned short)(r >> 16);
}

static __device__ __forceinline__ f32x4 mfma16(short8 a, short8 b, f32x4 c) {
  return __builtin_amdgcn_mfma_f32_16x16x32_bf16(
      __builtin_bit_cast(bf16x8, a), __builtin_bit_cast(bf16x8, b), c, 0, 0, 0);
}
static __device__ __forceinline__ f32x16 mfma32(short8 a, short8 b, f32x16 c) {
  return __builtin_amdgcn_mfma_f32_32x32x16_bf16(
      __builtin_bit_cast(bf16x8, a), __builtin_bit_cast(bf16x8, b), c, 0, 0, 0);
}

static __device__ __forceinline__ void gll16(const unsigned short* g, unsigned short* l) {
  __builtin_amdgcn_global_load_lds(
      (const __attribute__((address_space(1))) unsigned int*)(const void*)g,
      (__attribute__((address_space(3))) unsigned int*)(void*)l, 16, 0, 0);
}

static __device__ __forceinline__ unsigned cvtpk(float lo, float hi) {
  unsigned r;
  asm("v_cvt_pk_bf16_f32 %0, %1, %2" : "=v"(r) : "v"(lo), "v"(hi));
  return r;
}

static __device__ __forceinline__ void cvt8(const float* __restrict__ in,
                                            unsigned short* __restrict__ out, int i) {
  float4 a = ((const float4*)in)[i * 2];
  float4 b = ((const float4*)in)[i * 2 + 1];
  union { short8 v; unsigned short u[8]; } pk;
  pk.u[0] = f2bf(a.x); pk.u[1] = f2bf(a.y); pk.u[2] = f2bf(a.z); pk.u[3] = f2bf(a.w);
  pk.u[4] = f2bf(b.x); pk.u[5] = f2bf(b.y); pk.u[6] = f2bf(b.z); pk.u[7] = f2bf(b.w);
  ((short8*)out)[i] = pk.v;
}

// ---------- fused pre-pass: cvt q/k/v + 4 weights + maskpack ----------
__global__ __launch_bounds__(256)
void fused_pre(const float* __restrict__ queries, const float* __restrict__ keys,
               const float* __restrict__ values,
               const float* __restrict__ Wq, const float* __restrict__ Wk,
               const float* __restrict__ Wv, const float* __restrict__ Wo,
               const int* __restrict__ mask,
               unsigned short* __restrict__ Xq, unsigned short* __restrict__ Xk,
               unsigned short* __restrict__ Xv,
               unsigned short* __restrict__ W4, unsigned long long* __restrict__ M64)
{
  const int bid = blockIdx.x, tid = threadIdx.x;
  if (bid < 4096) {
    cvt8(queries, Xq, bid * 256 + tid);
  } else if (bid < 8192) {
    cvt8(keys, Xk, (bid - 4096) * 256 + tid);
  } else if (bid < 10240) {
    const int wsel = (bid - 8192) >> 9;
    const float* src = wsel == 0 ? Wq : wsel == 1 ? Wk : wsel == 2 ? Wv : Wo;
    cvt8(src, W4 + wsel * 1048576, ((bid - 8192) & 511) * 256 + tid);
  } else if (bid < 11264) {
    const int lane = tid & 63, wid = tid >> 6;
    const int gw = (bid - 10240) * 4 + wid;
#pragma unroll 4
    for (int j = 0; j < 32; ++j) {
      const int w = gw * 32 + j;
      unsigned long long b = __ballot(mask[(size_t)w * 64 + lane] != 0);
      if (lane == 0) M64[w] = b;
    }
  } else {
    cvt8(values, Xv, (bid - 11264) * 256 + tid);
  }
}

// ---------- 128x128 bf16 GEMM, BK=64 dbuf single-barrier, XOR-swizzled ----
// MODE 0: bf16 [M,1024], bias by col, oscale. MODE 2: f32 [M,1024].
// MODE 3: bf16 [1024][8192] (V^T = Wv @ Xv^T), bias by ROW, transposed blockmap.
// LDS tile row = 64 shorts (128B); chunk (8 shorts) swizzled: phys = log ^ (row&7).
template<int MODE>
__global__ __launch_bounds__(256)
void gemm_kernel(const unsigned short* __restrict__ A, const unsigned short* __restrict__ B,
                 const float* __restrict__ bias, void* __restrict__ outp, float oscale)
{
  __shared__ alignas(16) unsigned short As[2][8192];   // [128][64] x 2 bufs
  __shared__ alignas(16) unsigned short Bs[2][8192];
  const int tid = threadIdx.x, lane = tid & 63, wid = tid >> 6;
  const int l15 = lane & 15, lg = lane >> 4;
  const int j = blockIdx.x >> 3;
  int bm, bn;
  if (MODE == 3) { bn = (blockIdx.x & 7) * 8 + (j & 7); bm = j >> 3; }
  else           { bm = (blockIdx.x & 7) * 8 + (j & 7); bn = j >> 3; }
  const int wr = (wid >> 1) * 64, wc = (wid & 1) * 64;

  f32x4 acc[4][4] = {};

  // staging: 4 chunks/operand/thread; dest linear, source chunk pre-swizzled
  const unsigned short* gA[4];
  const unsigned short* gB[4];
  unsigned short* lA[4];
  unsigned short* lB[4];
#pragma unroll
  for (int i = 0; i < 4; ++i) {
    const int so = i * 2048 + tid * 8;            // shorts offset in tile
    const int row = so >> 6;                      // 0..127
    const int ch = (so >> 3) & 7;                 // logical 8-short chunk
    const int scol = (ch ^ (row & 7)) * 8;        // pre-swizzled source col
    gA[i] = A + (size_t)(bm * 128 + row) * 1024 + scol;
    gB[i] = B + (size_t)(bn * 128 + row) * 1024 + scol;
    lA[i] = &As[0][0] + so;
    lB[i] = &Bs[0][0] + so;
  }

  // prologue: stage k=0 into buf 0
#pragma unroll
  for (int i = 0; i < 4; ++i) { gll16(gA[i], lA[i]); gll16(gB[i], lB[i]); }

  int cur = 0;
#pragma unroll 2
  for (int k0 = 0; k0 < 1024; k0 += 64) {
    __syncthreads();   // drains vmcnt: buf[cur] staged; prev reads of buf[cur^1] done
    if (k0 + 64 < 1024) {
      const int nb = (cur ^ 1) * 8192;
#pragma unroll
      for (int i = 0; i < 4; ++i) {
        gll16(gA[i] + k0 + 64, lA[i] + nb);
        gll16(gB[i] + k0 + 64, lB[i] + nb);
      }
    }
    const unsigned short* Ab = &As[cur][0];
    const unsigned short* Bb = &Bs[cur][0];
#pragma unroll
    for (int h = 0; h < 2; ++h) {
      short8 af[4], bf[4];
#pragma unroll
      for (int f = 0; f < 4; ++f) {
        const int ra = wr + f * 16 + l15, rb = wc + f * 16 + l15;
        af[f] = *(const short8*)&Ab[ra * 64 + (((h * 4 + lg) ^ (ra & 7)) * 8)];
        bf[f] = *(const short8*)&Bb[rb * 64 + (((h * 4 + lg) ^ (rb & 7)) * 8)];
      }
#pragma unroll
      for (int r = 0; r < 4; ++r)
#pragma unroll
        for (int c = 0; c < 4; ++c)
          acc[r][c] = mfma16(af[r], bf[c], acc[r][c]);
    }
    cur ^= 1;
  }

#pragma unroll
  for (int r = 0; r < 4; ++r) {
    const int mb = bm * 128 + wr + r * 16 + lg * 4;
#pragma unroll
    for (int c = 0; c < 4; ++c) {
      const int col = bn * 128 + wc + c * 16 + l15;
      if (MODE == 0) {
        const float bv = bias[col];
        unsigned short* O = (unsigned short*)outp;
#pragma unroll
        for (int i = 0; i < 4; ++i)
          O[(size_t)(mb + i) * 1024 + col] = f2bf((acc[r][c][i] + bv) * oscale);
      } else if (MODE == 3) {      // V^T: row = e, col = m; bias by row; coalesced
        unsigned short* O = (unsigned short*)outp;
#pragma unroll
        for (int i = 0; i < 4; ++i)
          O[(size_t)(mb + i) * 8192 + col] = f2bf(acc[r][c][i] + bias[mb + i]);
      } else {
        const float bv = bias[col];
        float* O = (float*)outp;
#pragma unroll
        for (int i = 0; i < 4; ++i)
          O[(size_t)(mb + i) * 1024 + col] = acc[r][c][i] + bv;
      }
    }
  }
}

// ---------- flash attention: fragment-ordered LDS, m=0, lacc-MFMA l-sum ----------
// (frozen from R12)
__global__ __launch_bounds__(256)
void attn_kernel(const unsigned short* __restrict__ Q,   // [8192,1024] bf16 (scaled)
                 const unsigned short* __restrict__ K,   // [8192,1024] bf16
                 const unsigned short* __restrict__ VT,  // [1024][8192] bf16 (V^T)
                 const unsigned long long* __restrict__ M64,  // [N,1024,16]
                 unsigned short* __restrict__ AO)        // [8192,1024] bf16
{
  __shared__ alignas(16) unsigned short KV[2][8192];   // [K:0..4096][V:4096..8192]
  const int tid = threadIdx.x, lane = tid & 63, wid = tid >> 6;
  const int l31 = lane & 31, hi = lane >> 5, hi4 = hi * 4;
  const int w = (blockIdx.x & 7) * 128 + (blockIdx.x >> 3);   // XCD swizzle
  const int qt = w & 7, nh = w >> 3, h = nh & 15, n = nh >> 4;
  const int qbase = qt * 128 + wid * 32;

  const unsigned short* src[4];
  unsigned short* dst0[4];
  int tstride;
  if (wid < 2) {
#pragma unroll
    for (int i = 0; i < 4; ++i) {
      const int g = wid * 4 + i, c = g >> 1, kh = g & 1;
      src[i] = K + ((size_t)(n * 1024 + kh * 32 + l31) << 10) + h * 64 + c * 16 + hi * 8;
      dst0[i] = &KV[0][g * 512];
    }
    tstride = 64 * 1024;
  } else {
#pragma unroll
    for (int i = 0; i < 4; ++i) {
      const int g = (wid - 2) * 4 + i, kt = g >> 1, dh = g & 1;
      src[i] = VT + (size_t)(h * 64 + dh * 32 + l31) * 8192 + n * 1024 + kt * 16 + hi * 8;
      dst0[i] = &KV[0][4096 + g * 512];
    }
    tstride = 64;
  }

  short8 qf[4];
#pragma unroll
  for (int c = 0; c < 4; ++c)
    qf[c] = *(const short8*)&Q[(size_t)(n * 1024 + qbase + l31) * 1024 + h * 64 + c * 16 + hi * 8];

  const unsigned long long* Mq = M64 + (size_t)(n * 1024 + qbase + l31) * 16;
  unsigned long long mw = Mq[0], mwn = 0;

  f32x16 oacc0 = {}, oacc1 = {}, lacc = {};
  short8 ones;
#pragma unroll
  for (int j = 0; j < 8; ++j) ones[j] = (short)0x3F80;   // bf16 1.0

#pragma unroll
  for (int i = 0; i < 4; ++i) gll16(src[i], dst0[i]);

  int cur = 0;
#pragma unroll 2
  for (int t = 0; t < 16; ++t) {
    __syncthreads();
    if (t < 15) {
      const size_t off = (size_t)(t + 1) * tstride;
#pragma unroll
      for (int i = 0; i < 4; ++i) gll16(src[i] + off, dst0[i] + (cur ^ 1) * 8192);
      mwn = Mq[t + 1];
    }
    const unsigned short* Kb = &KV[cur][0];

    f32x16 s0 = {}, s1 = {};
    __builtin_amdgcn_s_setprio(1);
#pragma unroll
    for (int c = 0; c < 4; ++c) {
      short8 kf0 = *(const short8*)&Kb[(c * 2 + 0) * 512 + lane * 8];
      short8 kf1 = *(const short8*)&Kb[(c * 2 + 1) * 512 + lane * 8];
      s0 = mfma32(kf0, qf[c], s0);
      s1 = mfma32(kf1, qf[c], s1);
    }
    __builtin_amdgcn_s_setprio(0);

    const unsigned wlo = (unsigned)mw >> hi4;
    const unsigned whi = (unsigned)(mw >> 32) >> hi4;
#pragma unroll
    for (int kt = 0; kt < 2; ++kt) {
      const unsigned wsh = kt ? whi : wlo;
      const f32x16& sv = kt ? s1 : s0;
      float p[16];
#pragma unroll
      for (int r = 0; r < 16; ++r) {
        const float pe = exp2f(sv[r]);
        const int pos = 8 * (r >> 2) + (r & 3);
        const int msk = ((int)(wsh << (31 - pos))) >> 31;   // 0 or -1
        p[r] = __builtin_bit_cast(float, __builtin_bit_cast(int, pe) & msk);
      }
      unsigned u[4][2];
#pragma unroll
      for (int g = 0; g < 4; ++g) {
        u[g][0] = cvtpk(p[4 * g], p[4 * g + 1]);
        u[g][1] = cvtpk(p[4 * g + 2], p[4 * g + 3]);
      }
      short8 pa0, pa1;
#pragma unroll
      for (int m = 0; m < 2; ++m) {
        unsigned a0 = u[2 * m][0], b0 = u[2 * m + 1][0];
        unsigned a1 = u[2 * m][1], b1 = u[2 * m + 1][1];
        asm("v_permlane32_swap_b32 %0, %1" : "+v"(a0), "+v"(b0));
        asm("v_permlane32_swap_b32 %0, %1" : "+v"(a1), "+v"(b1));
        union { unsigned uu[4]; short8 v; } pk;
        pk.uu[0] = a0; pk.uu[1] = a1; pk.uu[2] = b0; pk.uu[3] = b1;
        if (m == 0) pa0 = pk.v; else pa1 = pk.v;
      }
      __builtin_amdgcn_s_setprio(1);
      {
        const int g0 = (kt * 2 + 0) * 2, g1 = (kt * 2 + 1) * 2;
        short8 vf00 = *(const short8*)&Kb[4096 + (g0 + 0) * 512 + lane * 8];
        short8 vf01 = *(const short8*)&Kb[4096 + (g0 + 1) * 512 + lane * 8];
        short8 vf10 = *(const short8*)&Kb[4096 + (g1 + 0) * 512 + lane * 8];
        short8 vf11 = *(const short8*)&Kb[4096 + (g1 + 1) * 512 + lane * 8];
        oacc0 = mfma32(pa0, vf00, oacc0);
        oacc1 = mfma32(pa0, vf01, oacc1);
        lacc  = mfma32(pa0, ones, lacc);
        oacc0 = mfma32(pa1, vf10, oacc0);
        oacc1 = mfma32(pa1, vf11, oacc1);
        lacc  = mfma32(pa1, ones, lacc);
      }
      __builtin_amdgcn_s_setprio(0);
    }

    mw = mwn;
    cur ^= 1;
  }

#pragma unroll
  for (int r = 0; r < 16; ++r) {
    const int qrow = 8 * (r >> 2) + (r & 3) + hi4;
    const float rl = 1.0f / lacc[r];
    const size_t row = (size_t)(n * 1024 + qbase + qrow) * 1024 + h * 64;
    AO[row + l31]      = f2bf(oacc0[r] * rl);
    AO[row + 32 + l31] = f2bf(oacc1[r] * rl);
  }
}

extern "C" void kernel_launch(void* const* d_in, const int* in_sizes, int n_in,
                              void* d_out, int out_size, void* d_ws, size_t ws_size,
                              hipStream_t stream) {
  (void)in_sizes; (void)n_in; (void)out_size; (void)ws_size;
  const float* values  = (const float*)d_in[0];
  const float* keys    = (const float*)d_in[1];
  const float* queries = (const float*)d_in[2];
  const int*   mask    = (const int*)d_in[3];
  const float* Wv = (const float*)d_in[4];
  const float* bv = (const float*)d_in[5];
  const float* Wk = (const float*)d_in[6];
  const float* bk = (const float*)d_in[7];
  const float* Wq = (const float*)d_in[8];
  const float* bq = (const float*)d_in[9];
  const float* Wo = (const float*)d_in[10];
  const float* bo = (const float*)d_in[11];

  const size_t MB = 1u << 20;
  char* ws = (char*)d_ws;
  unsigned short* R0  = (unsigned short*)(ws);             // Xq -> AO
  unsigned short* R16 = (unsigned short*)(ws + 16 * MB);   // Xk -> VTb
  unsigned short* Qb  = (unsigned short*)(ws + 32 * MB);
  unsigned short* Kb  = (unsigned short*)(ws + 48 * MB);
  unsigned short* W4  = (unsigned short*)(ws + 64 * MB);   // 4 x 1M shorts
  unsigned long long* M64 = (unsigned long long*)(ws + 72 * MB);  // 1MB
  unsigned short* Xv  = (unsigned short*)d_out;            // 16MB of d_out,
                                                           // dead until O-GEMM

  const dim3 b256(256);
  const float SCFULL = 0.03125f * 1.44269504089f;   // 1/sqrt(E) * log2(e)

  fused_pre<<<dim3(15360), b256, 0, stream>>>(
      queries, keys, values, Wq, Wk, Wv, Wo, mask, R0, R16, Xv, W4, M64);
  gemm_kernel<0><<<dim3(512), b256, 0, stream>>>(R0,  W4,           bq, (void*)Qb, SCFULL);
  gemm_kernel<0><<<dim3(512), b256, 0, stream>>>(R16, W4 + 1048576, bk, (void*)Kb, 1.0f);
  // V^T = Wv @ Xv^T  (A = Wv, B = Xv)  -> [1024][8192] coalesced
  gemm_kernel<3><<<dim3(512), b256, 0, stream>>>(W4 + 2 * 1048576, Xv,
                                                 bv, (void*)R16, 1.0f);
  attn_kernel<<<dim3(1024), b256, 0, stream>>>(Qb, Kb, R16, M64, R0 /*AO*/);
  gemm_kernel<2><<<dim3(512), b256, 0, stream>>>(R0, W4 + 3 * 1048576, bo, d_out, 1.0f);
}